// Round 8
// baseline (48.476 us; speedup 1.0000x reference)
//
#include <hip/hip_runtime.h>
#include <math.h>

#define FFT_N   4096
#define NT      256
#define PAIRS   4     // window-pairs per persistent block
// Padded LDS index: +1 float2 per 16 keeps every stage's strided access at
// the wave64 b64 floor (even bank-pair coverage, no above-floor conflicts).
#define PHYS(i) ((i) + ((i) >> 4))
#define LDS_SZ  (FFT_N + FFT_N / 16)

// LDS-only barrier: orders ds ops across the workgroup WITHOUT draining vmcnt,
// so cross-iteration global prefetch loads stay in flight (__syncthreads would
// emit s_waitcnt vmcnt(0) before s_barrier and kill the pipeline).
#define BAR() asm volatile("s_waitcnt lgkmcnt(0)\n\ts_barrier" ::: "memory")

// ext_vector float2 so clang lowers complex arithmetic to packed-fp32
// (v_pk_add_f32 / v_pk_fma_f32 with op_sel splat/swizzle + neg modifiers).
typedef float f2 __attribute__((ext_vector_type(2)));

__device__ __forceinline__ f2 cmul(f2 a, f2 b) {
    return (f2){a.x, a.x} * b + (f2){-a.y, a.y} * (f2){b.y, b.x};
}

// In-place 4-point DFT (w4 = -i); adds/subs are single pk ops.
__device__ __forceinline__ void dft4(f2& a, f2& b, f2& c, f2& d) {
    f2 t0 = a + c;
    f2 t1 = a - c;
    f2 t2 = b + d;
    f2 s  = b - d;
    f2 t3 = (f2){s.y, -s.x};  // -i*(b-d)
    a = t0 + t2;
    b = t1 + t3;
    c = t0 - t2;
    d = t1 - t3;
}

// 16-point DFT in registers via radix-4 x radix-4.
// Output DFT16[q1 + 4*q2] lands in v[4*q1 + q2] (reg = ((q&3)<<2)|(q>>2)).
__device__ __forceinline__ void dft16(f2 v[16]) {
    #pragma unroll
    for (int r1 = 0; r1 < 4; ++r1)
        dft4(v[r1], v[r1 + 4], v[r1 + 8], v[r1 + 12]);

    const float C1 = 0.92387953251128675613f;  // cos(pi/8)
    const float S1 = 0.38268343236508977173f;  // sin(pi/8)
    const float R2 = 0.70710678118654752440f;  // sqrt(2)/2
    v[5]  = cmul(v[5],  (f2){ C1, -S1});   // w16^1
    v[9]  = cmul(v[9],  (f2){ R2, -R2});   // w16^2
    v[13] = cmul(v[13], (f2){ S1, -C1});   // w16^3
    v[6]  = cmul(v[6],  (f2){ R2, -R2});   // w16^2
    v[10] = (f2){v[10].y, -v[10].x};       // w16^4 = -i
    v[14] = cmul(v[14], (f2){-R2, -R2});   // w16^6
    v[7]  = cmul(v[7],  (f2){ S1, -C1});   // w16^3
    v[11] = cmul(v[11], (f2){-R2, -R2});   // w16^6
    v[15] = cmul(v[15], (f2){-C1,  S1});   // w16^9
    #pragma unroll
    for (int q1 = 0; q1 < 4; ++q1)
        dft4(v[4 * q1], v[4 * q1 + 1], v[4 * q1 + 2], v[4 * q1 + 3]);
}

// Stage store with inter-stage twiddles built log-depth (dep chain ~4 deep).
template <int M>
__device__ __forceinline__ void store_stage_tw(f2* buf, int tid, f2 v[16]) {
    const int j = tid / M;
    const int k = tid % M;
    const int obase = j * 16 * M + k;
    float sn, cs;
    __sincosf((float)j * (-6.28318530717958647692f * (float)M / (float)FFT_N), &sn, &cs);
    f2 w[16];
    w[1]  = (f2){cs, sn};
    w[2]  = cmul(w[1], w[1]);
    w[3]  = cmul(w[2], w[1]);
    w[4]  = cmul(w[2], w[2]);
    w[5]  = cmul(w[4], w[1]);
    w[6]  = cmul(w[4], w[2]);
    w[7]  = cmul(w[4], w[3]);
    w[8]  = cmul(w[4], w[4]);
    w[9]  = cmul(w[8], w[1]);
    w[10] = cmul(w[8], w[2]);
    w[11] = cmul(w[8], w[3]);
    w[12] = cmul(w[8], w[4]);
    w[13] = cmul(w[8], w[5]);
    w[14] = cmul(w[8], w[6]);
    w[15] = cmul(w[8], w[7]);
    buf[PHYS(obase)] = v[0];
    #pragma unroll
    for (int q = 1; q < 16; ++q) {
        const int reg = ((q & 3) << 2) | (q >> 2);
        buf[PHYS(obase + q * M)] = cmul(v[reg], w[q]);
    }
}

__device__ __forceinline__ void load_stage(const f2* buf, int tid, f2 v[16]) {
    #pragma unroll
    for (int r = 0; r < 16; ++r) v[r] = buf[PHYS(tid + 256 * r)];
}

// Issue the 32 coalesced dword loads for one window-pair into registers.
__device__ __forceinline__ void issue_loads(const float* __restrict__ x,
                                            size_t pair, int t, f2 u[16]) {
    const float* __restrict__ p = x + pair * (size_t)(2 * FFT_N) + t;
    #pragma unroll
    for (int r = 0; r < 16; ++r)
        u[r] = (f2){p[256 * r], p[FFT_N + 256 * r]};
}

// FFT + symmetric power epilogue for one pair whose input is in v[].
__device__ __forceinline__ void do_pair(f2* buf, int t, f2 v[16],
                                        float* __restrict__ out, size_t pair) {
    // Stage 1 (M=1)
    dft16(v);
    store_stage_tw<1>(buf, t, v);
    BAR();

    // Stage 2 (M=16)
    load_stage(buf, t, v);
    BAR();
    dft16(v);
    store_stage_tw<16>(buf, t, v);
    BAR();

    // Stage 3 (M=256): j==0 -> no twiddles. Thread t ends holding Z[t+256q]
    // in v[reg(q)]. Only q=0 and q>=8 are ever read back as mirrors.
    load_stage(buf, t, v);
    BAR();
    dft16(v);
    buf[PHYS(t)] = v[0];
    #pragma unroll
    for (int q = 8; q < 16; ++q) {
        const int reg = ((q & 3) << 2) | (q >> 2);
        buf[PHYS(t + 256 * q)] = v[reg];
    }
    BAR();

    // Fused symmetric epilogue over k = t + 256q, q < 8 (k in [0, 2048)):
    // F1(k)=(Z(k)+conj(Z(N-k)))/2, F2(k)=(Z(k)-conj(Z(N-k)))/(2i);
    // real input -> |F(N-k)|^2 == |F(k)|^2, store both halves.
    float* __restrict__ o1 = out + pair * (size_t)(2 * FFT_N);
    float* __restrict__ o2 = o1 + FFT_N;
    #pragma unroll
    for (int q = 0; q < 8; ++q) {
        const int reg = ((q & 3) << 2) | (q >> 2);
        const int k = t + 256 * q;
        const int m = (FFT_N - k) & (FFT_N - 1);
        f2 zk = v[reg];
        f2 zn = buf[PHYS(m)];
        f2 zc = (f2){zn.x, -zn.y};       // conj(Z(N-k))
        f2 e1 = zk + zc;                  // 2*F1
        f2 e2 = zk - zc;                  // 2i*F2 (same magnitude as 2*F2)
        float p1 = 0.25f * (e1.x * e1.x + e1.y * e1.y);
        float p2 = 0.25f * (e2.x * e2.x + e2.y * e2.y);
        o1[k] = p1;
        o2[k] = p2;
        o1[m] = p1;  // k=0: same addr, same value
        o2[m] = p2;
    }
    if (t == 0) {  // k = 2048 self-mirror: F1 = Re(Z), F2 = Im(Z)
        f2 z = buf[PHYS(2048)];
        o1[2048] = z.x * z.x;
        o2[2048] = z.y * z.y;
    }
    BAR();  // mirror reads done before next iteration's stage-1 LDS store
}

// Persistent kernel: 1024 blocks (4/CU, all resident), PAIRS window-pairs
// each. While pair p runs its LDS stages, pair p+1's 32 input dwords are in
// flight into the other ping-pong register set -> continuous HBM streaming.
__global__ __launch_bounds__(NT) void spec_fft_kernel(const float* __restrict__ x,
                                                      float* __restrict__ out) {
    __shared__ f2 buf[LDS_SZ];
    const int t = threadIdx.x;
    const size_t p0 = (size_t)blockIdx.x * PAIRS;

    f2 A[16], B[16];
    issue_loads(x, p0, t, A);
    #pragma unroll
    for (int p = 0; p < PAIRS; ++p) {
        if (p & 1) {
            if (p + 1 < PAIRS) issue_loads(x, p0 + p + 1, t, A);
            do_pair(buf, t, B, out, p0 + p);
        } else {
            if (p + 1 < PAIRS) issue_loads(x, p0 + p + 1, t, B);
            do_pair(buf, t, A, out, p0 + p);
        }
    }
}

extern "C" void kernel_launch(void* const* d_in, const int* in_sizes, int n_in,
                              void* d_out, int out_size, void* d_ws, size_t ws_size,
                              hipStream_t stream) {
    const float* x = (const float*)d_in[0];
    float* out = (float*)d_out;
    const int nblk = (in_sizes[0] / FFT_N) / 2 / PAIRS;  // 8192/2/4 = 1024
    spec_fft_kernel<<<nblk, NT, 0, stream>>>(x, out);
}